// Round 7
// baseline (527.668 us; speedup 1.0000x reference)
//
#include <hip/hip_runtime.h>
#include <hip/hip_bf16.h>
#include <math.h>

// ---------------------------------------------------------------------------
// DotScaledAttention: q=(x0@Wq+bq)/sqrt(512); k=x1@Wk+bk; v=x2@Wk+bk;
// out = causal_softmax(q k^T) v.   B=8 N=2048 d_emb=1024 d_red=512, fp32 io.
// R4: proj 128x128 tiles + XCD-group swizzle (FETCH 808->130MB).
// R5: proj K-loop software pipeline (prefetch to regs under MFMA phase).
// R6/R7 (REVERTED): attn pipeline variants regressed.
// R8: attn 8KB chunks tri-buffer (LDS 33.8KB), nontemporal partial stores.
//     attn 205 -> <181us, total 527.
// R9: proj N-tile 256 (128x256 per block, grid 768). x-slab redundancy
// halves (4x->2x: ~786->~393MB of L3-path traffic) and per-barrier MFMA
// doubles (64/wave/kt) -> delivery latency amortized. acc[2][16] (AGPR),
// launch_bounds(256,2), LDS 55.3KB -> 2 blocks/CU.
// ---------------------------------------------------------------------------

typedef __bf16 bf16_t;
typedef __attribute__((ext_vector_type(8))) __bf16 bf16x8;
typedef __attribute__((ext_vector_type(4))) __bf16 bf16x4;
typedef __attribute__((ext_vector_type(4))) float f32x4;

#define MFMA16(a, b, c) __builtin_amdgcn_mfma_f32_16x16x32_bf16((a), (b), (c), 0, 0, 0)

#define XSTR 72  // LDS row stride (bf16 elems), 144B = 16B-aligned

__device__ __forceinline__ void stage16(const void* g, void* l) {
  // async global->LDS DMA, 16B per lane; LDS dest = wave-uniform base + lane*16
  __builtin_amdgcn_global_load_lds(
      (__attribute__((address_space(1))) void*)(uintptr_t)g,
      (__attribute__((address_space(3))) void*)l, 16, 0, 0);
}

// attn pipeline sync. Each wave stages 2x16B per 8KB chunk; chunk i+1 is
// issued just before this wait, so outstanding = {chunk i (2), chunk i+1 (2)}.
// 0x0F72 = vmcnt(2): chunk i drained, chunk i+1 stays in flight.
#define PW_MORE                                 \
  {                                             \
    asm volatile("" ::: "memory");              \
    __builtin_amdgcn_s_waitcnt(0x0F72);         \
    __builtin_amdgcn_s_barrier();               \
    asm volatile("" ::: "memory");              \
  }
#define PW_LAST                                 \
  {                                             \
    asm volatile("" ::: "memory");              \
    __builtin_amdgcn_s_waitcnt(0x0F70);         \
    __builtin_amdgcn_s_barrier();               \
    asm volatile("" ::: "memory");              \
  }

// proj barriers: A = ds_write visibility (lgkm drain only, no vmcnt drain);
// B = write-after-read protection, sched_barrier(0) pins MFMA above and the
// prefetch-consuming cvt/ds_write below, so the vmcnt wait lands post-MFMA.
#define PROJ_BAR_A                                    \
  {                                                   \
    asm volatile("s_waitcnt lgkmcnt(0)" ::: "memory"); \
    __builtin_amdgcn_s_barrier();                     \
    asm volatile("" ::: "memory");                    \
  }
#define PROJ_BAR_B                                    \
  {                                                   \
    __builtin_amdgcn_sched_barrier(0);                \
    __builtin_amdgcn_s_barrier();                     \
    asm volatile("" ::: "memory");                    \
  }

// --------------------------- W transpose + convert --------------------------
__global__ __launch_bounds__(256) void wt_kernel(const float* __restrict__ Wq,
                                                 const float* __restrict__ Wk,
                                                 bf16_t* __restrict__ Wtq,
                                                 bf16_t* __restrict__ Wtk) {
  __shared__ float tile[32][33];
  int bid = blockIdx.x;
  int mat = bid >> 9;
  int rem = bid & 511;
  int kt = rem >> 4, nt = rem & 15;
  int k0 = kt * 32, n0 = nt * 32;
  const float* src = mat ? Wk : Wq;
  bf16_t* dst = mat ? Wtk : Wtq;
  int t = threadIdx.x;
  int r = t >> 3, c4 = (t & 7) * 4;
  float4 v = *(const float4*)(src + (k0 + r) * 512 + n0 + c4);
  tile[r][c4 + 0] = v.x; tile[r][c4 + 1] = v.y;
  tile[r][c4 + 2] = v.z; tile[r][c4 + 3] = v.w;
  __syncthreads();
  bf16x4 o;
  o[0] = (bf16_t)tile[c4 + 0][r];
  o[1] = (bf16_t)tile[c4 + 1][r];
  o[2] = (bf16_t)tile[c4 + 2][r];
  o[3] = (bf16_t)tile[c4 + 3][r];
  *(bf16x4*)(dst + (n0 + r) * 1024 + k0 + c4) = o;
}

// ------------------------------- projections --------------------------------
// R9: 128x256 output tile per block. Grid = 768 = 3 mats x 128 mblk x 2 nblk.
// Swizzle: xcd = bid&7; i = bid>>3 (0..95); nblk = i&1; g = (i>>1)*8 + xcd
// (0..383 bijective); mat = g>>7; mblk = g&127.  The 2 nblk jobs of a
// (mat,mblk) group land on the SAME XCD -> 512KB x-slab fetched once,
// second consumer hits L2/L3.
__global__ __launch_bounds__(256, 2) void proj_kernel(
    const float* __restrict__ x0, const float* __restrict__ x1, const float* __restrict__ x2,
    const bf16_t* __restrict__ Wtq, const bf16_t* __restrict__ Wtk,
    const float* __restrict__ bq, const float* __restrict__ bk,
    bf16_t* __restrict__ qo, bf16_t* __restrict__ ko, bf16_t* __restrict__ vT) {
  __shared__ __align__(16) bf16_t Xs[128 * XSTR];   // 18 KB
  __shared__ __align__(16) bf16_t Ws[256 * XSTR];   // 36 KB
  int bid = blockIdx.x;
  int xcd = bid & 7;
  int i5 = bid >> 3;           // 0..95
  int nblk = i5 & 1;           // 0..1  (256-wide output column tile)
  int g = (i5 >> 1) * 8 + xcd; // 0..383 bijective
  int mat = g >> 7;            // 0..2
  int mblk = g & 127;          // 0..127
  const float* xsrc = (mat == 0) ? x0 : ((mat == 1) ? x1 : x2);
  const bf16_t* wsrc = (mat == 0) ? Wtq : Wtk;
  int tid = threadIdx.x;
  int wave = tid >> 6, lane = tid & 63, lhi = lane >> 4, llo = lane & 15;

  f32x4 acc[2][16];
#pragma unroll
  for (int i = 0; i < 2; ++i)
#pragma unroll
    for (int j = 0; j < 16; ++j) acc[i][j] = (f32x4){0.f, 0.f, 0.f, 0.f};

  int xrow = tid >> 1, xseg = tid & 1;   // 128 rows x 2 segs of 32 K-elems
  int wrow = tid;                        // 256 rows x 64 K-elems (full row)
  const float* xbase = xsrc + (size_t)(mblk * 128 + xrow) * 1024 + xseg * 32;
  const bf16_t* wbase = wsrc + (size_t)(nblk * 256 + wrow) * 1024;

  // prefetch registers (kt+1's data lives here during kt's MFMA phase)
  float4 nx[8];
  bf16x8 nw[8];

  // prologue: load kt=0 and stage to LDS
#pragma unroll
  for (int i = 0; i < 8; ++i) nx[i] = *(const float4*)(xbase + i * 4);
#pragma unroll
  for (int i = 0; i < 8; ++i) nw[i] = *(const bf16x8*)(wbase + i * 8);
  {
    bf16_t tmp[32];
#pragma unroll
    for (int i = 0; i < 8; ++i) {
      tmp[i * 4 + 0] = (bf16_t)nx[i].x; tmp[i * 4 + 1] = (bf16_t)nx[i].y;
      tmp[i * 4 + 2] = (bf16_t)nx[i].z; tmp[i * 4 + 3] = (bf16_t)nx[i].w;
    }
#pragma unroll
    for (int i = 0; i < 4; ++i)
      *(bf16x8*)(&Xs[xrow * XSTR + xseg * 32 + i * 8]) = *(bf16x8*)(&tmp[i * 8]);
#pragma unroll
    for (int i = 0; i < 8; ++i)
      *(bf16x8*)(&Ws[wrow * XSTR + i * 8]) = nw[i];
  }

  for (int kt = 0; kt < 16; ++kt) {
    PROJ_BAR_A;  // ds_writes visible; prefetch loads NOT drained
    if (kt < 15) {
      int k0 = (kt + 1) * 64;
#pragma unroll
      for (int i = 0; i < 8; ++i) nx[i] = *(const float4*)(xbase + k0 + i * 4);
#pragma unroll
      for (int i = 0; i < 8; ++i) nw[i] = *(const bf16x8*)(wbase + k0 + i * 8);
    }
    // MFMA phase on the current LDS tile (loads in flight underneath)
#pragma unroll
    for (int ks = 0; ks < 2; ++ks) {
      bf16x8 af[2], bfr[16];
#pragma unroll
      for (int mt = 0; mt < 2; ++mt)
        af[mt] = *(const bf16x8*)(&Xs[(wave * 32 + mt * 16 + llo) * XSTR + ks * 32 + lhi * 8]);
#pragma unroll
      for (int nt = 0; nt < 16; ++nt)
        bfr[nt] = *(const bf16x8*)(&Ws[(nt * 16 + llo) * XSTR + ks * 32 + lhi * 8]);
#pragma unroll
      for (int mt = 0; mt < 2; ++mt)
#pragma unroll
        for (int nt = 0; nt < 16; ++nt)
          acc[mt][nt] = MFMA16(af[mt], bfr[nt], acc[mt][nt]);
    }
    if (kt < 15) {
      PROJ_BAR_B;  // reads done; vmcnt wait for nx/nw lands HERE, post-MFMA
      bf16_t tmp[32];
#pragma unroll
      for (int i = 0; i < 8; ++i) {
        tmp[i * 4 + 0] = (bf16_t)nx[i].x; tmp[i * 4 + 1] = (bf16_t)nx[i].y;
        tmp[i * 4 + 2] = (bf16_t)nx[i].z; tmp[i * 4 + 3] = (bf16_t)nx[i].w;
      }
#pragma unroll
      for (int i = 0; i < 4; ++i)
        *(bf16x8*)(&Xs[xrow * XSTR + xseg * 32 + i * 8]) = *(bf16x8*)(&tmp[i * 8]);
#pragma unroll
      for (int i = 0; i < 8; ++i)
        *(bf16x8*)(&Ws[wrow * XSTR + i * 8]) = nw[i];
    }
  }

  const float* bias = (mat == 0) ? bq : bk;
  float scale = (mat == 0) ? 0.044194173824159216f : 1.0f;  // 1/sqrt(512)
#pragma unroll
  for (int mt = 0; mt < 2; ++mt) {
#pragma unroll
    for (int nt = 0; nt < 16; ++nt) {
      int n = nblk * 256 + nt * 16 + llo;
      float bv = bias[n];
      int rowb = mblk * 128 + wave * 32 + mt * 16 + lhi * 4;
      float vals[4];
#pragma unroll
      for (int r = 0; r < 4; ++r) vals[r] = (acc[mt][nt][r] + bv) * scale;
      if (mat == 0) {
#pragma unroll
        for (int r = 0; r < 4; ++r) qo[(size_t)(rowb + r) * 512 + n] = (bf16_t)vals[r];
      } else if (mat == 1) {
#pragma unroll
        for (int r = 0; r < 4; ++r) ko[(size_t)(rowb + r) * 512 + n] = (bf16_t)vals[r];
      } else {
        int batch = rowb >> 11, tok = rowb & 2047;
        bf16x4 o;
        o[0] = (bf16_t)vals[0]; o[1] = (bf16_t)vals[1];
        o[2] = (bf16_t)vals[2]; o[3] = (bf16_t)vals[3];
        *(bf16x4*)(vT + (size_t)(batch * 512 + n) * 2048 + tok) = o;
      }
    }
  }
}

// ------------------------- attention: staging helpers ------------------------
// K chunk: 64 keys x 64 d (d-range cd*64..) -> 8KB. 2 granules per lane.
// granule idx: key = idx>>3 (8 granules/row), p = idx&7, s = p^(key&7)
__device__ __forceinline__ void issueK8(const bf16_t* kbase, int key0, int cd,
                                        bf16_t* buf, int wave, int lane) {
#pragma unroll
  for (int i = 0; i < 2; ++i) {
    int idx = wave * 128 + i * 64 + lane;
    int key = idx >> 3, p = idx & 7;
    int s = p ^ (key & 7);
    stage16(kbase + (size_t)(key0 + key) * 512 + cd * 64 + s * 8,
            buf + (size_t)(wave * 128 + i * 64) * 8);
  }
}
// V chunk: 64 d (cv*64..) x 64 keys -> 8KB.
// granule idx: dl = idx>>3, p = idx&7, s = p^(dl&7)
__device__ __forceinline__ void issueV8(const bf16_t* vbase, int key0, int cv,
                                        bf16_t* buf, int wave, int lane) {
#pragma unroll
  for (int i = 0; i < 2; ++i) {
    int idx = wave * 128 + i * 64 + lane;
    int dl = idx >> 3, p = idx & 7;
    int s = p ^ (dl & 7);
    stage16(vbase + (size_t)(cv * 64 + dl) * 2048 + key0 + s * 8,
            buf + (size_t)(wave * 128 + i * 64) * 8);
  }
}

// ------------------------------- attention ----------------------------------
// 816 jobs: batch = blockIdx&7 (XCD pin), jj = blockIdx>>3 in 0..101 decodes
// (t desc from 31, n_t = ceil((t+1)/6) chunks). Block = 64 q-rows, 4 waves.
// Per kb: 16 phases of 8KB chunks (K0..K7, V0..V7). Tri-buffer (chunk -> %3);
// chunk j+1 issued at phase j start (buf last read at phase j-2: WAR-safe),
// waited at phase j+1 via vmcnt(2). LDS 33.8KB -> 4 blocks/CU by LDS.
__global__ __launch_bounds__(256, 2) void attn_kernel(
    const bf16_t* __restrict__ qg, const bf16_t* __restrict__ kg,
    const bf16_t* __restrict__ vTg, float* __restrict__ out,
    bf16_t* __restrict__ Opart, float* __restrict__ msum, float* __restrict__ lsum) {
  __shared__ __align__(16) bf16_t Pipe[3][4096];       // 24KB tri-buffer (8KB each)
  __shared__ __align__(16) bf16_t Plds[4][16 * XSTR];  // 9.2KB per-wave P

  int bid = blockIdx.x;
  int b = bid & 7, jj = bid >> 3;
  int t = 31, base = 0, n = 6;
  for (;;) {
    int nt_ = (t + 6) / 6;
    if (jj < base + nt_) { n = nt_; break; }
    base += nt_; --t;
  }
  int c = jj - base;
  int kbs = t + 1;
  int csz = (kbs + n - 1) / n;
  int kb_lo = c * csz;
  int kb_hi = min(kbs, kb_lo + csz);
  int q0 = t * 64;

  int tid = threadIdx.x;
  int wave = tid >> 6, lane = tid & 63, lhi = lane >> 4, llo = lane & 15;
  bf16_t* Pb = &Plds[wave][0];

  const bf16_t* kbase = kg + ((size_t)b << 11) * 512;
  const bf16_t* vbase = vTg + ((size_t)b << 9) * 2048;

  int bc = 0;  // compute buffer (= chunk index % 3)
  issueK8(kbase, kb_lo * 64, 0, &Pipe[0][0], wave, lane);

  // Q fragments (A-layout m=llo, k=lhi*8+j), rows q0+wave*16+llo, all 512 d
  const bf16_t* qrowp = qg + (size_t)((b << 11) + q0 + wave * 16 + llo) * 512;
  bf16x8 qf[16];
#pragma unroll
  for (int kk = 0; kk < 16; ++kk)
    qf[kk] = *(const bf16x8*)(qrowp + kk * 32 + lhi * 8);

  f32x4 Of[32];
#pragma unroll
  for (int i = 0; i < 32; ++i) Of[i] = (f32x4){0.f, 0.f, 0.f, 0.f};
  float m_i[4] = {-INFINITY, -INFINITY, -INFINITY, -INFINITY};
  float l_i[4] = {0.f, 0.f, 0.f, 0.f};

  for (int kb = kb_lo; kb < kb_hi; ++kb) {
    int key0 = kb * 64;
    bool more = (kb + 1 < kb_hi);
    f32x4 sf[4];
#pragma unroll
    for (int nt = 0; nt < 4; ++nt) sf[nt] = (f32x4){0.f, 0.f, 0.f, 0.f};

    // ---- QK: 8 phases of 64-d K chunks; issue chunk j+1 at phase j ----
#pragma unroll
    for (int cd = 0; cd < 8; ++cd) {
      int nb = (bc + 1 == 3) ? 0 : bc + 1;
      if (cd < 7) issueK8(kbase, key0, cd + 1, &Pipe[nb][0], wave, lane);
      else        issueV8(vbase, key0, 0, &Pipe[nb][0], wave, lane);
      PW_MORE;
      const bf16_t* bufc = &Pipe[bc][0];
#pragma unroll
      for (int kkl = 0; kkl < 2; ++kkl) {
#pragma unroll
        for (int nt = 0; nt < 4; ++nt) {
          bf16x8 kf = *(const bf16x8*)(bufc + (nt * 16 + llo) * 64 +
                                       (((kkl * 4 + lhi) ^ (llo & 7)) * 8));
          sf[nt] = MFMA16(qf[cd * 2 + kkl], kf, sf[nt]);
        }
      }
      bc = nb;
    }

    // ---- softmax (V0 DMA in flight underneath) ----
    if (kb == t) {  // diagonal block: causal mask
#pragma unroll
      for (int nt = 0; nt < 4; ++nt) {
        int kloc = nt * 16 + llo;
#pragma unroll
        for (int r = 0; r < 4; ++r)
          if (kloc > wave * 16 + lhi * 4 + r) sf[nt][r] = -INFINITY;
      }
    }
    float vm[4];
#pragma unroll
    for (int r = 0; r < 4; ++r) {
      vm[r] = fmaxf(fmaxf(sf[0][r], sf[1][r]), fmaxf(sf[2][r], sf[3][r]));
      vm[r] = fmaxf(vm[r], __shfl_xor(vm[r], 1, 64));
      vm[r] = fmaxf(vm[r], __shfl_xor(vm[r], 2, 64));
      vm[r] = fmaxf(vm[r], __shfl_xor(vm[r], 4, 64));
      vm[r] = fmaxf(vm[r], __shfl_xor(vm[r], 8, 64));
    }
    float alpha[4];
    int resc = 0;
#pragma unroll
    for (int r = 0; r < 4; ++r) {
      float mn = fmaxf(m_i[r], vm[r]);
      alpha[r] = __expf(m_i[r] - mn);
      m_i[r] = mn;
      resc |= (alpha[r] < 1.0f) ? 1 : 0;
    }
#pragma unroll
    for (int r = 0; r < 4; ++r) {
      float ps = 0.f;
#pragma unroll
      for (int nt = 0; nt < 4; ++nt) {
        float p2 = __expf(sf[nt][r] - m_i[r]);
        ps += p2;
        Pb[(lhi * 4 + r) * XSTR + nt * 16 + llo] = (bf16_t)p2;
      }
      l_i[r] = alpha[r] * l_i[r] + ps;
    }
    if (__any(resc)) {
#pragma unroll
      for (int i = 0; i < 32; ++i)
#pragma unroll
        for (int r = 0; r < 4; ++r) Of[i][r] *= alpha[r];
    }

    // ---- PV: 8 phases of 64-d V chunks; last phase issues next kb's K0 ----
#pragma unroll
    for (int cv = 0; cv < 8; ++cv) {
      int nb = (bc + 1 == 3) ? 0 : bc + 1;
      bool last = (cv == 7) && !more;
      if (cv < 7)      issueV8(vbase, key0, cv + 1, &Pipe[nb][0], wave, lane);
      else if (more)   issueK8(kbase, key0 + 64, 0, &Pipe[nb][0], wave, lane);
      if (last) PW_LAST else PW_MORE;
      const bf16_t* bufc = &Pipe[bc][0];
#pragma unroll
      for (int ks = 0; ks < 2; ++ks) {
        bf16x8 pa = *(const bf16x8*)(&Pb[llo * XSTR + ks * 32 + lhi * 8]);
#pragma unroll
        for (int ntl = 0; ntl < 4; ++ntl) {
          bf16x8 bv = *(const bf16x8*)(bufc + (ntl * 16 + llo) * 64 +
                                       (((ks * 4 + lhi) ^ (llo & 7)) * 8));
          Of[cv * 4 + ntl] = MFMA16(pa, bv, Of[cv * 4 + ntl]);
        }
      }
      bc = nb;
    }
  }  // kb loop

  // l reduction across the 16 col-lanes
#pragma unroll
  for (int r = 0; r < 4; ++r) {
    l_i[r] += __shfl_xor(l_i[r], 1, 64);
    l_i[r] += __shfl_xor(l_i[r], 2, 64);
    l_i[r] += __shfl_xor(l_i[r], 4, 64);
    l_i[r] += __shfl_xor(l_i[r], 8, 64);
  }

  // Of[i] holds d-col = i*16 + llo
  if (n == 1) {
    float linv[4];
#pragma unroll
    for (int r = 0; r < 4; ++r) linv[r] = 1.0f / l_i[r];
    float* ob = out + (size_t)((b << 11) + q0 + wave * 16) * 512;
#pragma unroll
    for (int i = 0; i < 32; ++i) {
      int dcol = i * 16 + llo;
#pragma unroll
      for (int r = 0; r < 4; ++r)
        __builtin_nontemporal_store(Of[i][r] * linv[r],
                                    &ob[(size_t)(lhi * 4 + r) * 512 + dcol]);
    }
  } else {
    bf16_t* op = Opart + (size_t)bid * (64 * 512) + (size_t)(wave * 16) * 512;
#pragma unroll
    for (int i = 0; i < 32; ++i) {
      int dcol = i * 16 + llo;
#pragma unroll
      for (int r = 0; r < 4; ++r)
        __builtin_nontemporal_store((bf16_t)Of[i][r],
                                    &op[(size_t)(lhi * 4 + r) * 512 + dcol]);
    }
    if (llo == 0) {
#pragma unroll
      for (int r = 0; r < 4; ++r) {
        msum[bid * 64 + wave * 16 + lhi * 4 + r] = m_i[r];
        lsum[bid * 64 + wave * 16 + lhi * 4 + r] = l_i[r];
      }
    }
  }
}

// ------------------------------- merge --------------------------------------
// Combine 2-6 partials for tiles 6..31 of each batch.
__global__ __launch_bounds__(256) void merge_kernel(const bf16_t* __restrict__ Opart,
                                                    const float* __restrict__ msum,
                                                    const float* __restrict__ lsum,
                                                    float* __restrict__ out) {
  int idx = blockIdx.x * 256 + threadIdx.x;  // 8*26*64*512 = 6,815,744
  int d = idx & 511;
  int rg = idx >> 9;          // 0..13311 = b(8) x t(26) x row(64)
  int b = rg / 1664;
  int rr = rg - b * 1664;
  int t = 6 + (rr >> 6), row = rr & 63;
  int base = 0;
  for (int s = 31; s > t; --s) base += (s + 6) / 6;
  int n = (t + 6) / 6;
  float M = -INFINITY;
  for (int c2 = 0; c2 < n; ++c2)
    M = fmaxf(M, msum[((base + c2) * 8 + b) * 64 + row]);
  float denom = 0.f, acc = 0.f;
  for (int c2 = 0; c2 < n; ++c2) {
    int j = (base + c2) * 8 + b;
    float a = __expf(msum[j * 64 + row] - M);
    denom += a * lsum[j * 64 + row];
    bf16_t ov = __builtin_nontemporal_load(&Opart[(size_t)j * (64 * 512) + row * 512 + d]);
    acc += a * (float)ov;
  }
  __builtin_nontemporal_store(acc / denom,
                              &out[(size_t)((b << 11) + (t << 6) + row) * 512 + d]);
}

// ------------------------------- launcher -----------------------------------
extern "C" void kernel_launch(void* const* d_in, const int* in_sizes, int n_in,
                              void* d_out, int out_size, void* d_ws, size_t ws_size,
                              hipStream_t stream) {
  (void)in_sizes; (void)n_in; (void)out_size; (void)ws_size;
  const float* x0 = (const float*)d_in[0];
  const float* x1 = (const float*)d_in[1];
  const float* x2 = (const float*)d_in[2];
  const float* Wq = (const float*)d_in[3];
  const float* bq = (const float*)d_in[4];
  const float* Wk = (const float*)d_in[5];
  const float* bk = (const float*)d_in[6];
  float* out = (float*)d_out;
  char* ws = (char*)d_ws;
  const size_t MB = 1ull << 20;
  bf16_t* Wtq = (bf16_t*)(ws + 0 * MB);             // 1 MB
  bf16_t* Wtk = (bf16_t*)(ws + 1 * MB);             // 1 MB
  bf16_t* qw  = (bf16_t*)(ws + 2 * MB);             // 16 MB
  bf16_t* kw  = (bf16_t*)(ws + 18 * MB);            // 16 MB
  bf16_t* vT  = (bf16_t*)(ws + 34 * MB);            // 16 MB
  float* msum = (float*)(ws + 50 * MB);             // 209 KB (816*64*4)
  float* lsum = (float*)(ws + 50 * MB + (512 << 10));
  bf16_t* Opart = (bf16_t*)(ws + 51 * MB);          // 53.5 MB (816*64*512*2)

  hipLaunchKernelGGL(wt_kernel, dim3(1024), dim3(256), 0, stream, Wq, Wk, Wtq, Wtk);
  hipLaunchKernelGGL(proj_kernel, dim3(768), dim3(256), 0, stream,
                     x0, x1, x2, Wtq, Wtk, bq, bk, qw, kw, vT);
  hipLaunchKernelGGL(attn_kernel, dim3(816), dim3(256), 0, stream,
                     qw, kw, vT, out, Opart, msum, lsum);
  hipLaunchKernelGGL(merge_kernel, dim3(26624), dim3(256), 0, stream,
                     Opart, msum, lsum, out);
}